// Round 10
// baseline (3434.991 us; speedup 1.0000x reference)
//
#include <hip/hip_runtime.h>
#include <cmath>

#define B_  32
#define T_  250
#define E_  256
#define U_  1024
#define FU_ 4096   // 4*U
#define VK_ 1280   // virtual K = U + E  ( [rk0 ; k0] )
#define NT_ 40     // A/B k-tiles (32 h-tiles + 8 x-tiles)

typedef __attribute__((ext_vector_type(8)))  __bf16 bf16x8;
typedef __attribute__((ext_vector_type(4)))  float  f32x4;

__device__ __forceinline__ float sigf(float x) { return 1.f / (1.f + __expf(-x)); }

// ---------------------------------------------------------------------------
// One-time: transpose + hi/lo-split weights into MFMA B-fragment order
// (proven rounds 7-9). wfrag[((bi*40 + K)*64 + l)*8 + j].
// ---------------------------------------------------------------------------
__global__ __launch_bounds__(256) void wsplit_kernel(
    const float* __restrict__ rk0, const float* __restrict__ k0,
    __bf16* __restrict__ wfh, __bf16* __restrict__ wfl)
{
    __shared__ float tile[32][65];
    const int tid = threadIdx.x;
    const int jt  = blockIdx.x & 63;
    const int kt  = blockIdx.x >> 6;
    const int gk0 = kt * 32;
    const int j0  = jt * 64;

    {
        const int c = tid & 63, r4 = tid >> 6;
        #pragma unroll
        for (int i = 0; i < 8; ++i) {
            const int r  = r4 * 8 + i;
            const int gk = gk0 + r;
            const float* src = (gk < U_) ? (rk0 + (size_t)gk * FU_ + j0 + c)
                                         : (k0 + (size_t)(gk - U_) * FU_ + j0 + c);
            tile[r][c] = *src;
        }
    }
    __syncthreads();
    {
        const int j_loc = tid >> 2, kseg = tid & 3;
        bf16x8 hi, lo;
        #pragma unroll
        for (int i = 0; i < 8; ++i) {
            const float  v  = tile[kseg * 8 + i][j_loc];
            const __bf16 hv = (__bf16)v;
            hi[i] = hv;
            lo[i] = (__bf16)(v - (float)hv);
        }
        const int col = j0 + j_loc;
        const int g   = col >> 10;
        const int u   = col & 1023;
        const int bi  = u >> 2;
        const int c   = g * 4 + (u & 3);
        const int l   = kseg * 16 + c;
        const size_t off = (((size_t)bi * NT_ + kt) * 64 + l) * 8;
        *(bf16x8*)(wfh + off) = hi;
        *(bf16x8*)(wfl + off) = lo;
    }
}

// ---------------------------------------------------------------------------
// Seed x(0) fragments (hi only) into af0 x-tiles. 1 block x 256 threads.
// Plain stores are fine: kernel-end flush makes them LLC-visible before mega.
// ---------------------------------------------------------------------------
__global__ __launch_bounds__(256) void xsplit_kernel(
    const int* __restrict__ tokens, const float* __restrict__ emb,
    __bf16* __restrict__ af, int t)
{
    const int tid2 = threadIdx.x;
    const int b   = tid2 >> 3;
    const int kc  = (tid2 & 7) * 32;
    const int tok = tokens[b * T_ + t];
    const float* ep = emb + (size_t)tok * E_ + kc;
    const int Kt  = 32 + (kc >> 5);
    const int mt2 = b >> 4;
    #pragma unroll
    for (int g8 = 0; g8 < 4; ++g8) {
        bf16x8 hi;
        #pragma unroll
        for (int j = 0; j < 8; ++j) hi[j] = (__bf16)ep[g8 * 8 + j];
        const int lane2 = g8 * 16 + (b & 15);
        const size_t off = (((size_t)Kt * 2 + mt2) * 64 + lane2) * 8;
        *(bf16x8*)(af + off) = hi;
    }
}

// ---------------------------------------------------------------------------
// PERSISTENT cooperative LSTM: all 250 steps in ONE dispatch.
// Grid 256 x 512 (1 block/CU, co-resident). Block bi = units [4bi,4bi+4) x
// 4 gates over full K=1280; wave w = (mt=w&1, kq=w>>2? no: kq=w>>1).
// Custom two-level LLC barrier instead of cg::grid_sync (42us measured):
//   - h/x ping-pong + flags via RELAXED AGENT-scope atomics (sc1 -> served at
//     Infinity Cache). NO acquire fence -> no buffer_inv -> W stays L2-hot.
//   - __syncthreads drains vmcnt(0) (documented) => h-stores are LLC-complete
//     before tid0's arrival add.
//   - 8 leaf counters (bi&7) -> root -> monotonic flag = step+1. Counters
//     reset BEFORE flag release: next-step arrivals are flag-gated, no race.
// Markidis reduced: A = h as bf16-hi only (err ~1e-3 << 1.03e-2 threshold);
// W keeps hi+lo -> 2 MFMA + 2 atomic-8B A-loads + 2 cached W-loads per tile.
// c-state in registers (tid<32 owns (b=tid, 4 units)).
// ---------------------------------------------------------------------------
__global__ __launch_bounds__(512) void lstm_mega(
    const __bf16* __restrict__ wfh, const __bf16* __restrict__ wfl,
    const int* __restrict__ tokens, const float* __restrict__ emb,
    const float* __restrict__ b0,
    __bf16* __restrict__ af0, __bf16* __restrict__ af1,
    int* __restrict__ bar)          // [0..7] leaf, [8] root, [9] flag (zeroed)
{
    __shared__ float part[4][32][18];

    const int tid  = threadIdx.x;
    const int lane = tid & 63;
    const int w    = tid >> 6;
    const int mt   = w & 1;
    const int kq   = w >> 1;
    const int bi   = blockIdx.x;
    const int u0   = bi * 4;

    const __bf16* wbh = wfh + ((size_t)bi * NT_) * 512 + lane * 8;
    const __bf16* wbl = wfl + ((size_t)bi * NT_) * 512 + lane * 8;

    float cr0 = 0.f, cr1 = 0.f, cr2 = 0.f, cr3 = 0.f;   // c for (b=tid, u0..u0+3)

    for (int t = 0; t < T_; ++t) {
        const __bf16* ar = (t & 1) ? af1 : af0;
        __bf16*       aw = (t & 1) ? af0 : af1;

        // ---- GEMM: 10 uniform k-tiles per wave ----
        f32x4 acc_h = {}, acc_l = {};
        #pragma unroll
        for (int s = 0; s < 10; ++s) {
            const int K = kq * 10 + s;
            const bf16x8 wh = *(const bf16x8*)(wbh + (size_t)K * 512);
            const bf16x8 wl = *(const bf16x8*)(wbl + (size_t)K * 512);
            const unsigned long long* ap = (const unsigned long long*)
                (ar + ((size_t)(K * 2 + mt) * 64 + lane) * 8);
            union { unsigned long long q[2]; bf16x8 v; } au;
            au.q[0] = __hip_atomic_load(ap,     __ATOMIC_RELAXED, __HIP_MEMORY_SCOPE_AGENT);
            au.q[1] = __hip_atomic_load(ap + 1, __ATOMIC_RELAXED, __HIP_MEMORY_SCOPE_AGENT);
            acc_h = __builtin_amdgcn_mfma_f32_16x16x32_bf16(au.v, wh, acc_h, 0, 0, 0);
            acc_l = __builtin_amdgcn_mfma_f32_16x16x32_bf16(au.v, wl, acc_l, 0, 0, 0);
        }
        #pragma unroll
        for (int r = 0; r < 4; ++r)
            part[kq][mt * 16 + (lane >> 4) * 4 + r][lane & 15] = acc_h[r] + acc_l[r];

        // ---- x(t+1) prefetch: 1 thread/block, partitioned over 256 blocks ----
        if (tid == 128 && t + 1 < T_) {
            const int b2  = bi >> 3;
            const int kc  = (bi & 7) * 32;
            const int tok = tokens[b2 * T_ + t + 1];
            const float* ep = emb + (size_t)tok * E_ + kc;
            const int Kt  = 32 + (bi & 7);
            const int mt2 = b2 >> 4;
            #pragma unroll
            for (int g8 = 0; g8 < 4; ++g8) {
                union { unsigned long long q[2]; bf16x8 v; } hu;
                #pragma unroll
                for (int j = 0; j < 8; ++j) hu.v[j] = (__bf16)ep[g8 * 8 + j];
                const size_t off = (((size_t)Kt * 2 + mt2) * 64 + g8 * 16 + (b2 & 15)) * 8;
                unsigned long long* dp = (unsigned long long*)(aw + off);
                __hip_atomic_store(dp,     hu.q[0], __ATOMIC_RELAXED, __HIP_MEMORY_SCOPE_AGENT);
                __hip_atomic_store(dp + 1, hu.q[1], __ATOMIC_RELAXED, __HIP_MEMORY_SCOPE_AGENT);
            }
        }
        __syncthreads();

        // ---- pointwise: tid<32 -> (b=tid, units u0..u0+3), c in regs ----
        if (tid < 32) {
            const int b = tid;
            union { unsigned long long q; unsigned short s4[4]; } pk;
            #pragma unroll
            for (int uu = 0; uu < 4; ++uu) {
                float z0 = b0[0 * U_ + u0 + uu];
                float z1 = b0[1 * U_ + u0 + uu];
                float z2 = b0[2 * U_ + u0 + uu];
                float z3 = b0[3 * U_ + u0 + uu];
                #pragma unroll
                for (int q = 0; q < 4; ++q) {
                    z0 += part[q][b][ 0 + uu];
                    z1 += part[q][b][ 4 + uu];
                    z2 += part[q][b][ 8 + uu];
                    z3 += part[q][b][12 + uu];
                }
                const float ii = sigf(z0), ff = sigf(z1);
                const float gg = tanhf(z2), oo = sigf(z3);
                float cprev = (uu == 0) ? cr0 : (uu == 1) ? cr1 : (uu == 2) ? cr2 : cr3;
                const float cv = ff * cprev + ii * gg;
                if (uu == 0) cr0 = cv; else if (uu == 1) cr1 = cv;
                else if (uu == 2) cr2 = cv; else cr3 = cv;
                const float hv = oo * tanhf(cv);
                union { __bf16 h; unsigned short u; } cvt;
                cvt.h = (__bf16)hv;
                pk.s4[uu] = cvt.u;
            }
            const size_t fob = (((size_t)(u0 >> 5) * 2 + (b >> 4)) * 64
                                + ((u0 >> 3) & 3) * 16 + (b & 15)) * 8 + (u0 & 7);
            __hip_atomic_store((unsigned long long*)(aw + fob), pk.q,
                               __ATOMIC_RELAXED, __HIP_MEMORY_SCOPE_AGENT);
        }
        __syncthreads();   // drains vmcnt(0) for ALL waves -> stores LLC-complete

        // ---- custom grid barrier (skip after last step) ----
        if (t + 1 < T_) {
            if (tid == 0) {
                int* leaf = bar + (bi & 7);
                const int n = __hip_atomic_fetch_add(leaf, 1, __ATOMIC_RELAXED,
                                                     __HIP_MEMORY_SCOPE_AGENT);
                if (n == 31) {
                    __hip_atomic_store(leaf, 0, __ATOMIC_RELAXED, __HIP_MEMORY_SCOPE_AGENT);
                    const int m = __hip_atomic_fetch_add(bar + 8, 1, __ATOMIC_RELAXED,
                                                         __HIP_MEMORY_SCOPE_AGENT);
                    if (m == 7) {
                        __hip_atomic_store(bar + 8, 0, __ATOMIC_RELAXED,
                                           __HIP_MEMORY_SCOPE_AGENT);
                        __hip_atomic_store(bar + 9, t + 1, __ATOMIC_RELAXED,
                                           __HIP_MEMORY_SCOPE_AGENT);
                    }
                }
                while (__hip_atomic_load(bar + 9, __ATOMIC_RELAXED,
                                         __HIP_MEMORY_SCOPE_AGENT) < t + 1)
                    __builtin_amdgcn_s_sleep(2);
            }
            __syncthreads();
        }
    }
}

// ---------------------------------------------------------------------------
// Cell-1 z (fp32, off critical path): Pc[b][col] = x_last @ k1 + b1.
// ---------------------------------------------------------------------------
__global__ __launch_bounds__(256) void cell1_gemm(
    const int* __restrict__ tokens, const float* __restrict__ emb,
    const float* __restrict__ k1, const float* __restrict__ b1,
    float* __restrict__ Pc)
{
    const int tid  = threadIdx.x;
    const int lane = tid & 63;
    const int warp = tid >> 6;
    const int j  = blockIdx.x;
    const int ct = j & 15, bg = j >> 4;
    const int b  = bg * 4 + warp;
    const int col = ct * 256 + lane * 4;
    const int tok = tokens[b * T_ + (T_ - 1)];
    const float* wp = k1 + col;
    const float* xp = emb + (size_t)tok * E_;
    float4 acc = *reinterpret_cast<const float4*>(b1 + col);
    #pragma unroll 4
    for (int k4 = 0; k4 < 64; ++k4) {
        const float4 x4 = *reinterpret_cast<const float4*>(xp + k4 * 4);
        const float4 w0 = *reinterpret_cast<const float4*>(wp + (size_t)(k4 * 4 + 0) * FU_);
        const float4 w1 = *reinterpret_cast<const float4*>(wp + (size_t)(k4 * 4 + 1) * FU_);
        const float4 w2 = *reinterpret_cast<const float4*>(wp + (size_t)(k4 * 4 + 2) * FU_);
        const float4 w3 = *reinterpret_cast<const float4*>(wp + (size_t)(k4 * 4 + 3) * FU_);
        acc.x = fmaf(x4.x, w0.x, acc.x); acc.y = fmaf(x4.x, w0.y, acc.y);
        acc.z = fmaf(x4.x, w0.z, acc.z); acc.w = fmaf(x4.x, w0.w, acc.w);
        acc.x = fmaf(x4.y, w1.x, acc.x); acc.y = fmaf(x4.y, w1.y, acc.y);
        acc.z = fmaf(x4.y, w1.z, acc.z); acc.w = fmaf(x4.y, w1.w, acc.w);
        acc.x = fmaf(x4.z, w2.x, acc.x); acc.y = fmaf(x4.z, w2.y, acc.y);
        acc.z = fmaf(x4.z, w2.z, acc.z); acc.w = fmaf(x4.z, w2.w, acc.w);
        acc.x = fmaf(x4.w, w3.x, acc.x); acc.y = fmaf(x4.w, w3.y, acc.y);
        acc.z = fmaf(x4.w, w3.z, acc.z); acc.w = fmaf(x4.w, w3.w, acc.w);
    }
    *reinterpret_cast<float4*>(Pc + (size_t)b * FU_ + col) = acc;
}

// ---------------------------------------------------------------------------
// Final: out[b] = sigmoid( h0.wout[0:U] + h1.wout[U:2U] + bout ).
// h0 from A-fragment layout (bf16 hi only); h1 on the fly from Pc.
// ---------------------------------------------------------------------------
__global__ __launch_bounds__(256) void final_kernel(
    const __bf16* __restrict__ hfh,
    const float* __restrict__ Pc,
    const float* __restrict__ wout, const float* __restrict__ bout,
    float* __restrict__ out)
{
    const int b = blockIdx.x;
    const int tid = threadIdx.x;
    float s = 0.f;
    for (int u = tid; u < U_; u += 256) {
        const size_t fo = ((size_t)((u >> 5) * 2 + (b >> 4)) * 64
                           + ((u >> 3) & 3) * 16 + (b & 15)) * 8 + (u & 7);
        const float h0v = (float)hfh[fo];
        const float zi = Pc[(size_t)b * FU_ + u];
        const float zg = Pc[(size_t)b * FU_ + 2 * U_ + u];
        const float zo = Pc[(size_t)b * FU_ + 3 * U_ + u];
        const float c1 = sigf(zi) * tanhf(zg);
        const float h1 = sigf(zo) * tanhf(c1);
        s += h0v * wout[u] + h1 * wout[U_ + u];
    }
    #pragma unroll
    for (int off = 32; off > 0; off >>= 1) s += __shfl_down(s, off, 64);
    __shared__ float partf[4];
    if ((tid & 63) == 0) partf[tid >> 6] = s;
    __syncthreads();
    if (tid == 0) {
        const float tot = partf[0] + partf[1] + partf[2] + partf[3] + bout[0];
        out[b] = 1.f / (1.f + __expf(-tot));
    }
}

extern "C" void kernel_launch(void* const* d_in, const int* in_sizes, int n_in,
                              void* d_out, int out_size, void* d_ws, size_t ws_size,
                              hipStream_t stream) {
    const int*   tokens = (const int*)  d_in[0];
    const float* emb    = (const float*)d_in[1];
    const float* k0     = (const float*)d_in[2];
    const float* rk0    = (const float*)d_in[3];
    const float* b0     = (const float*)d_in[4];
    const float* k1     = (const float*)d_in[5];
    // d_in[6] = rk1 unused: cell 1 runs from zero state.
    const float* b1     = (const float*)d_in[7];
    const float* wout   = (const float*)d_in[8];
    const float* bout   = (const float*)d_in[9];
    float* out = (float*)d_out;

    const size_t BFU  = (size_t)B_ * FU_;          // 131072
    const size_t AFSZ = (size_t)NT_ * 2 * 64 * 8;  // 40960 bf16 (80 KB)
    const size_t WSZ  = (size_t)FU_ * VK_;         // 5242880

    __bf16* af0 = (__bf16*)d_ws;               // A-frag parity0 (hi only, 80 KB)
    int*    bar = (int*)(af0 + AFSZ);          // 16 ints: leaf[8], root, flag
    __bf16* af1 = (__bf16*)(bar + 16);         // A-frag parity1 (80 KB)
    __bf16* wfh = af1 + AFSZ;                  // W frag hi (10.5 MB)
    __bf16* wfl = wfh + WSZ;                   // W frag lo (10.5 MB)
    float*  Pc  = (float*)(wfl + WSZ);         // [32][4096] f32 (512 KB)
    // ws use ~= 21.6 MB

    // zero af0 (h-tiles -> h(0)=0) + barrier state, every call (replay-safe)
    hipMemsetAsync(af0, 0, AFSZ * sizeof(__bf16) + 16 * sizeof(int), stream);

    wsplit_kernel<<<2560, 256, 0, stream>>>(rk0, k0, wfh, wfl);
    xsplit_kernel<<<1, 256, 0, stream>>>(tokens, emb, af0, 0);
    cell1_gemm<<<128, 256, 0, stream>>>(tokens, emb, k1, b1, Pc);

    {
        void* args[] = {
            (void*)&wfh, (void*)&wfl, (void*)&tokens, (void*)&emb,
            (void*)&b0, (void*)&af0, (void*)&af1, (void*)&bar
        };
        hipLaunchCooperativeKernel((void*)lstm_mega,
                                   dim3(256), dim3(512), args, 0, stream);
    }
    // T_=250 even: t=249 writes parity 0 -> final h in af0.

    final_kernel<<<B_, 256, 0, stream>>>(af0, Pc, wout, bout, out);
}

// Round 11
// 1496.527 us; speedup vs baseline: 2.2953x; 2.2953x over previous
//
#include <hip/hip_runtime.h>
#include <cmath>

#define B_  32
#define T_  250
#define E_  256
#define U_  1024
#define FU_ 4096   // 4*U
#define VK_ 1280   // virtual K = U + E  ( [rk0 ; k0] )
#define NT_ 40     // W k-tiles (32 h-tiles + 8 x-tiles)

typedef __attribute__((ext_vector_type(8)))  __bf16 bf16x8;
typedef __attribute__((ext_vector_type(4)))  float  f32x4;

__device__ __forceinline__ float sigf(float x) { return 1.f / (1.f + __expf(-x)); }

// ---------------------------------------------------------------------------
// One-time: transpose + hi/lo-split weights into MFMA B-fragment order
// (proven rounds 7-10). wfrag[((bi*40 + K)*64 + l)*8 + j].
// ---------------------------------------------------------------------------
__global__ __launch_bounds__(256) void wsplit_kernel(
    const float* __restrict__ rk0, const float* __restrict__ k0,
    __bf16* __restrict__ wfh, __bf16* __restrict__ wfl)
{
    __shared__ float tile[32][65];
    const int tid = threadIdx.x;
    const int jt  = blockIdx.x & 63;
    const int kt  = blockIdx.x >> 6;
    const int gk0 = kt * 32;
    const int j0  = jt * 64;

    {
        const int c = tid & 63, r4 = tid >> 6;
        #pragma unroll
        for (int i = 0; i < 8; ++i) {
            const int r  = r4 * 8 + i;
            const int gk = gk0 + r;
            const float* src = (gk < U_) ? (rk0 + (size_t)gk * FU_ + j0 + c)
                                         : (k0 + (size_t)(gk - U_) * FU_ + j0 + c);
            tile[r][c] = *src;
        }
    }
    __syncthreads();
    {
        const int j_loc = tid >> 2, kseg = tid & 3;
        bf16x8 hi, lo;
        #pragma unroll
        for (int i = 0; i < 8; ++i) {
            const float  v  = tile[kseg * 8 + i][j_loc];
            const __bf16 hv = (__bf16)v;
            hi[i] = hv;
            lo[i] = (__bf16)(v - (float)hv);
        }
        const int col = j0 + j_loc;
        const int g   = col >> 10;
        const int u   = col & 1023;
        const int bi  = u >> 2;
        const int c   = g * 4 + (u & 3);
        const int l   = kseg * 16 + c;
        const size_t off = (((size_t)bi * NT_ + kt) * 64 + l) * 8;
        *(bf16x8*)(wfh + off) = hi;
        *(bf16x8*)(wfl + off) = lo;
    }
}

// ---------------------------------------------------------------------------
// One-time: x-fragments (bf16 hi only) for ALL 250 steps.
// Grid 250 (block = t) x 256 threads; thread = (b=tid>>3, 32-k chunk).
// xf[(((t*8 + Kx)*2 + mt)*64 + lane)*8 + j]; lane = g8*16 + (b&15)
// -> matches A-frag mapping row=lane&15, k=(lane>>4)*8+j (proven r7-10).
// ---------------------------------------------------------------------------
__global__ __launch_bounds__(256) void xsplit_all(
    const int* __restrict__ tokens, const float* __restrict__ emb,
    __bf16* __restrict__ xf)
{
    const int t   = blockIdx.x;
    const int tid = threadIdx.x;
    const int b   = tid >> 3;
    const int kc  = (tid & 7) * 32;
    const int tok = tokens[b * T_ + t];
    const float* ep = emb + (size_t)tok * E_ + kc;
    const int Kx = kc >> 5;          // x-tile 0..7
    const int mt = b >> 4;
    #pragma unroll
    for (int g8 = 0; g8 < 4; ++g8) {
        bf16x8 hi;
        #pragma unroll
        for (int j = 0; j < 8; ++j) hi[j] = (__bf16)ep[g8 * 8 + j];
        const int lane2 = g8 * 16 + (b & 15);
        const size_t off = ((((size_t)t * 8 + Kx) * 2 + mt) * 64 + lane2) * 8;
        *(bf16x8*)(xf + off) = hi;
    }
}

// ---------------------------------------------------------------------------
// Fused LSTM step, launched 250x (stream order = grid barrier; proven the
// cheapest sync: r5 cg::sync 42us, r10 custom LLC barrier ~15us, relaunch
// ~2us). Grid 256 x 512. Block bi = units [4bi,4bi+4) x 4 gates, full K.
// A = bf16-hi ONLY (r10 validated absmax 0.0) -> 2 MFMA/tile (Ah@Wh + Ah@Wl).
// h-tiles (K<32) from ping-pong h-frag buffer; x-tiles (K>=32) from the
// precomputed xf[t] — no emb gather, no in-step prefetch, no stragglers.
// ---------------------------------------------------------------------------
__global__ __launch_bounds__(512) void step_fused(
    const __bf16* __restrict__ wfh, const __bf16* __restrict__ wfl,
    const float* __restrict__ b0,
    const __bf16* __restrict__ af_r, __bf16* __restrict__ af_w,
    const __bf16* __restrict__ xf,
    float* __restrict__ c_st, int t)
{
    __shared__ float part[4][32][18];

    const int tid  = threadIdx.x;
    const int lane = tid & 63;
    const int w    = tid >> 6;          // 8 waves
    const int mt   = w & 1;             // m-tile (batches mt*16..mt*16+15)
    const int kq   = w >> 1;            // K-quarter (10 k-tiles)
    const int bi   = blockIdx.x;

    const __bf16* wbh = wfh + ((size_t)bi * NT_) * 512 + lane * 8;
    const __bf16* wbl = wfl + ((size_t)bi * NT_) * 512 + lane * 8;
    const __bf16* xft = xf + ((size_t)t * 8 * 2) * 512;

    f32x4 acc_h = {}, acc_l = {};

    #pragma unroll
    for (int s = 0; s < 10; ++s) {
        const int K = kq * 10 + s;      // tile 0..39
        const bf16x8 wh = *(const bf16x8*)(wbh + (size_t)K * 512);
        const bf16x8 wl = *(const bf16x8*)(wbl + (size_t)K * 512);
        const __bf16* asrc = (K < 32)
            ? (af_r + ((size_t)(K * 2 + mt) * 64 + lane) * 8)
            : (xft + ((size_t)((K - 32) * 2 + mt) * 64 + lane) * 8);
        const bf16x8 ah = *(const bf16x8*)asrc;
        acc_h = __builtin_amdgcn_mfma_f32_16x16x32_bf16(ah, wh, acc_h, 0, 0, 0);
        acc_l = __builtin_amdgcn_mfma_f32_16x16x32_bf16(ah, wl, acc_l, 0, 0, 0);
    }

    // --- kq-partial exchange ---
    #pragma unroll
    for (int r = 0; r < 4; ++r) {
        const int row = mt * 16 + (lane >> 4) * 4 + r;
        part[kq][row][lane & 15] = acc_h[r] + acc_l[r];
    }
    __syncthreads();

    // --- pointwise: reduce kq partials, gates, c/h update ---
    if (tid < 128) {
        const int b  = tid >> 2, uu = tid & 3;
        const int u0 = bi * 4;
        float z[4];
        #pragma unroll
        for (int g = 0; g < 4; ++g) {
            const int c = g * 4 + uu;
            float s2 = b0[g * U_ + u0 + uu];
            #pragma unroll
            for (int q = 0; q < 4; ++q) s2 += part[q][b][c];
            z[g] = s2;
        }
        const float ii = sigf(z[0]), ff = sigf(z[1]);
        const float gg = tanhf(z[2]), oo = sigf(z[3]);
        const int ci = b * U_ + u0 + uu;
        const float cv = ff * c_st[ci] + ii * gg;
        c_st[ci] = cv;
        const float hv = oo * tanhf(cv);
        const int u = u0 + uu;
        const size_t fo = ((size_t)((u >> 5) * 2 + (b >> 4)) * 64
                           + ((u >> 3) & 3) * 16 + (b & 15)) * 8 + (u & 7);
        af_w[fo] = (__bf16)hv;
    }
}

// ---------------------------------------------------------------------------
// Cell-1 z (fp32, off critical path): Pc[b][col] = x_last @ k1 + b1.
// ---------------------------------------------------------------------------
__global__ __launch_bounds__(256) void cell1_gemm(
    const int* __restrict__ tokens, const float* __restrict__ emb,
    const float* __restrict__ k1, const float* __restrict__ b1,
    float* __restrict__ Pc)
{
    const int tid  = threadIdx.x;
    const int lane = tid & 63;
    const int warp = tid >> 6;
    const int j  = blockIdx.x;
    const int ct = j & 15, bg = j >> 4;
    const int b  = bg * 4 + warp;
    const int col = ct * 256 + lane * 4;
    const int tok = tokens[b * T_ + (T_ - 1)];
    const float* wp = k1 + col;
    const float* xp = emb + (size_t)tok * E_;
    float4 acc = *reinterpret_cast<const float4*>(b1 + col);
    #pragma unroll 4
    for (int k4 = 0; k4 < 64; ++k4) {
        const float4 x4 = *reinterpret_cast<const float4*>(xp + k4 * 4);
        const float4 w0 = *reinterpret_cast<const float4*>(wp + (size_t)(k4 * 4 + 0) * FU_);
        const float4 w1 = *reinterpret_cast<const float4*>(wp + (size_t)(k4 * 4 + 1) * FU_);
        const float4 w2 = *reinterpret_cast<const float4*>(wp + (size_t)(k4 * 4 + 2) * FU_);
        const float4 w3 = *reinterpret_cast<const float4*>(wp + (size_t)(k4 * 4 + 3) * FU_);
        acc.x = fmaf(x4.x, w0.x, acc.x); acc.y = fmaf(x4.x, w0.y, acc.y);
        acc.z = fmaf(x4.x, w0.z, acc.z); acc.w = fmaf(x4.x, w0.w, acc.w);
        acc.x = fmaf(x4.y, w1.x, acc.x); acc.y = fmaf(x4.y, w1.y, acc.y);
        acc.z = fmaf(x4.y, w1.z, acc.z); acc.w = fmaf(x4.y, w1.w, acc.w);
        acc.x = fmaf(x4.z, w2.x, acc.x); acc.y = fmaf(x4.z, w2.y, acc.y);
        acc.z = fmaf(x4.z, w2.z, acc.z); acc.w = fmaf(x4.z, w2.w, acc.w);
        acc.x = fmaf(x4.w, w3.x, acc.x); acc.y = fmaf(x4.w, w3.y, acc.y);
        acc.z = fmaf(x4.w, w3.z, acc.z); acc.w = fmaf(x4.w, w3.w, acc.w);
    }
    *reinterpret_cast<float4*>(Pc + (size_t)b * FU_ + col) = acc;
}

// ---------------------------------------------------------------------------
// Final: out[b] = sigmoid( h0.wout[0:U] + h1.wout[U:2U] + bout ).
// h0 from A-fragment layout (bf16 hi); h1 on the fly from Pc.
// ---------------------------------------------------------------------------
__global__ __launch_bounds__(256) void final_kernel(
    const __bf16* __restrict__ hfh,
    const float* __restrict__ Pc,
    const float* __restrict__ wout, const float* __restrict__ bout,
    float* __restrict__ out)
{
    const int b = blockIdx.x;
    const int tid = threadIdx.x;
    float s = 0.f;
    for (int u = tid; u < U_; u += 256) {
        const size_t fo = ((size_t)((u >> 5) * 2 + (b >> 4)) * 64
                           + ((u >> 3) & 3) * 16 + (b & 15)) * 8 + (u & 7);
        const float h0v = (float)hfh[fo];
        const float zi = Pc[(size_t)b * FU_ + u];
        const float zg = Pc[(size_t)b * FU_ + 2 * U_ + u];
        const float zo = Pc[(size_t)b * FU_ + 3 * U_ + u];
        const float c1 = sigf(zi) * tanhf(zg);
        const float h1 = sigf(zo) * tanhf(c1);
        s += h0v * wout[u] + h1 * wout[U_ + u];
    }
    #pragma unroll
    for (int off = 32; off > 0; off >>= 1) s += __shfl_down(s, off, 64);
    __shared__ float partf[4];
    if ((tid & 63) == 0) partf[tid >> 6] = s;
    __syncthreads();
    if (tid == 0) {
        const float tot = partf[0] + partf[1] + partf[2] + partf[3] + bout[0];
        out[b] = 1.f / (1.f + __expf(-tot));
    }
}

extern "C" void kernel_launch(void* const* d_in, const int* in_sizes, int n_in,
                              void* d_out, int out_size, void* d_ws, size_t ws_size,
                              hipStream_t stream) {
    const int*   tokens = (const int*)  d_in[0];
    const float* emb    = (const float*)d_in[1];
    const float* k0     = (const float*)d_in[2];
    const float* rk0    = (const float*)d_in[3];
    const float* b0     = (const float*)d_in[4];
    const float* k1     = (const float*)d_in[5];
    // d_in[6] = rk1 unused: cell 1 runs from zero state.
    const float* b1     = (const float*)d_in[7];
    const float* wout   = (const float*)d_in[8];
    const float* bout   = (const float*)d_in[9];
    float* out = (float*)d_out;

    const size_t BU   = (size_t)B_ * U_;           // 32768
    const size_t BFU  = (size_t)B_ * FU_;          // 131072
    const size_t AFSZ = (size_t)32 * 2 * 64 * 8;   // h-frag elems (64 KB)
    const size_t XFSZ = (size_t)T_ * 8 * 2 * 64 * 8; // x-frag elems (1.6 MB)
    const size_t WSZ  = (size_t)FU_ * VK_;         // 5242880

    float*  c    = (float*)d_ws;               // [32][1024] f32   (128 KB)
    __bf16* af0  = (__bf16*)(c + BU);          // h-frag parity0   (64 KB)
    __bf16* af1  = af0 + AFSZ;                 // h-frag parity1
    __bf16* xf   = af1 + AFSZ;                 // x-frags, all t   (1.6 MB)
    __bf16* wfh  = xf + XFSZ;                  // W frag hi (10.5 MB)
    __bf16* wfl  = wfh + WSZ;                  // W frag lo (10.5 MB)
    float*  Pc   = (float*)(wfl + WSZ);        // [32][4096] f32  (512 KB)
    // ws use ~= 23.4 MB

    // zero c + h-frag parity0 (contiguous) every call (replay-safe)
    hipMemsetAsync(c, 0, BU * sizeof(float) + AFSZ * sizeof(__bf16), stream);

    wsplit_kernel<<<2560, 256, 0, stream>>>(rk0, k0, wfh, wfl);
    xsplit_all<<<T_, 256, 0, stream>>>(tokens, emb, xf);
    cell1_gemm<<<128, 256, 0, stream>>>(tokens, emb, k1, b1, Pc);

    for (int t = 0; t < T_; ++t) {
        const __bf16* ar = (t & 1) ? af1 : af0;
        __bf16*       aw = (t & 1) ? af0 : af1;
        step_fused<<<256, 512, 0, stream>>>(wfh, wfl, b0, ar, aw, xf, c, t);
    }
    // T_=250 even: t=249 reads af1, writes af0 -> final h in af0.

    final_kernel<<<B_, 256, 0, stream>>>(af0, Pc, wout, bout, out);
}

// Round 12
// 1125.548 us; speedup vs baseline: 3.0518x; 1.3296x over previous
//
#include <hip/hip_runtime.h>
#include <cmath>

#define B_  32
#define T_  250
#define E_  256
#define U_  1024
#define FU_ 4096   // 4*U
#define VK_ 1280   // virtual K = U + E  ( [rk0 ; k0] )
#define NT_ 40     // W k-tiles (32 h-tiles + 8 x-tiles)

typedef __attribute__((ext_vector_type(8)))  __bf16 bf16x8;
typedef __attribute__((ext_vector_type(4)))  float  f32x4;

__device__ __forceinline__ float sigf(float x) { return 1.f / (1.f + __expf(-x)); }

// ---------------------------------------------------------------------------
// One-time: transpose weights into MFMA B-fragment order, bf16 HI ONLY
// (W-lo Markidis term dropped; r10 validated the same-magnitude A-lo drop).
// wfrag[((bi*40 + K)*64 + l)*8 + j]  (layout proven rounds 7-11).
// ---------------------------------------------------------------------------
__global__ __launch_bounds__(256) void wsplit_kernel(
    const float* __restrict__ rk0, const float* __restrict__ k0,
    __bf16* __restrict__ wfh)
{
    __shared__ float tile[32][65];
    const int tid = threadIdx.x;
    const int jt  = blockIdx.x & 63;
    const int kt  = blockIdx.x >> 6;
    const int gk0 = kt * 32;
    const int j0  = jt * 64;

    {
        const int c = tid & 63, r4 = tid >> 6;
        #pragma unroll
        for (int i = 0; i < 8; ++i) {
            const int r  = r4 * 8 + i;
            const int gk = gk0 + r;
            const float* src = (gk < U_) ? (rk0 + (size_t)gk * FU_ + j0 + c)
                                         : (k0 + (size_t)(gk - U_) * FU_ + j0 + c);
            tile[r][c] = *src;
        }
    }
    __syncthreads();
    {
        const int j_loc = tid >> 2, kseg = tid & 3;
        bf16x8 hi;
        #pragma unroll
        for (int i = 0; i < 8; ++i)
            hi[i] = (__bf16)tile[kseg * 8 + i][j_loc];
        const int col = j0 + j_loc;
        const int g   = col >> 10;
        const int u   = col & 1023;
        const int bi  = u >> 2;
        const int c   = g * 4 + (u & 3);
        const int l   = kseg * 16 + c;
        const size_t off = (((size_t)bi * NT_ + kt) * 64 + l) * 8;
        *(bf16x8*)(wfh + off) = hi;
    }
}

// ---------------------------------------------------------------------------
// One-time: x-fragments (bf16 hi) for ALL 250 steps (proven round 11).
// xf[(((t*8 + Kx)*2 + mt)*64 + lane)*8 + j].
// ---------------------------------------------------------------------------
__global__ __launch_bounds__(256) void xsplit_all(
    const int* __restrict__ tokens, const float* __restrict__ emb,
    __bf16* __restrict__ xf)
{
    const int t   = blockIdx.x;
    const int tid = threadIdx.x;
    const int b   = tid >> 3;
    const int kc  = (tid & 7) * 32;
    const int tok = tokens[b * T_ + t];
    const float* ep = emb + (size_t)tok * E_ + kc;
    const int Kx = kc >> 5;
    const int mt = b >> 4;
    #pragma unroll
    for (int g8 = 0; g8 < 4; ++g8) {
        bf16x8 hi;
        #pragma unroll
        for (int j = 0; j < 8; ++j) hi[j] = (__bf16)ep[g8 * 8 + j];
        const int lane2 = g8 * 16 + (b & 15);
        const size_t off = ((((size_t)t * 8 + Kx) * 2 + mt) * 64 + lane2) * 8;
        *(bf16x8*)(xf + off) = hi;
    }
}

// ---------------------------------------------------------------------------
// Fused LSTM step, launched 250x (stream order = grid barrier; proven
// cheapest: cg::sync 42us (r5), LLC barrier ~15us (r10), relaunch ~2us).
// Grid 256 x 512. Block bi = units [4bi,4bi+4) x 4 gates, full K=1280.
// Wave = kq (0..7, 5 k-tiles each); mt handled INSIDE the wave so each W
// fragment is loaded once and feeds both m-tiles from registers:
// per wave 5 W-loads + 10 A-loads + 10 MFMA (r11 had 30 loads, 20 MFMA).
// A = bf16-hi, W = bf16-hi (1 MFMA/tile). Layouts proven r7-11.
// ---------------------------------------------------------------------------
__global__ __launch_bounds__(512) void step_fused(
    const __bf16* __restrict__ wfh,
    const float* __restrict__ b0,
    const __bf16* __restrict__ af_r, __bf16* __restrict__ af_w,
    const __bf16* __restrict__ xf,
    float* __restrict__ c_st, int t)
{
    __shared__ float part[8][32][18];   // [kq][row][col], stride 18

    const int tid  = threadIdx.x;
    const int lane = tid & 63;
    const int kq   = tid >> 6;          // 8 waves = 8 K-slices (5 tiles each)
    const int bi   = blockIdx.x;

    const __bf16* wbh = wfh + ((size_t)bi * NT_) * 512 + lane * 8;
    const __bf16* xft = xf + ((size_t)t * 8 * 2) * 512;

    f32x4 acc0 = {}, acc1 = {};

    #pragma unroll
    for (int s = 0; s < 5; ++s) {
        const int K = kq * 5 + s;       // tile 0..39
        const bf16x8 wh = *(const bf16x8*)(wbh + (size_t)K * 512);
        const __bf16* abase = (K < 32)
            ? (af_r + ((size_t)(K * 2) * 64 + lane) * 8)
            : (xft + ((size_t)((K - 32) * 2) * 64 + lane) * 8);
        const bf16x8 a0 = *(const bf16x8*)abase;            // mt = 0
        const bf16x8 a1 = *(const bf16x8*)(abase + 512);    // mt = 1
        acc0 = __builtin_amdgcn_mfma_f32_16x16x32_bf16(a0, wh, acc0, 0, 0, 0);
        acc1 = __builtin_amdgcn_mfma_f32_16x16x32_bf16(a1, wh, acc1, 0, 0, 0);
    }

    // --- kq-partial exchange (C: col=lane&15, row=(lane>>4)*4+r) ---
    #pragma unroll
    for (int r = 0; r < 4; ++r) {
        const int rr = (lane >> 4) * 4 + r;
        part[kq][rr][lane & 15]      = acc0[r];
        part[kq][16 + rr][lane & 15] = acc1[r];
    }
    __syncthreads();

    // --- pointwise: reduce 8 kq partials, gates, c/h update ---
    if (tid < 128) {
        const int b  = tid >> 2, uu = tid & 3;
        const int u0 = bi * 4;
        float z[4];
        #pragma unroll
        for (int g = 0; g < 4; ++g) {
            const int c = g * 4 + uu;
            float s2 = b0[g * U_ + u0 + uu];
            #pragma unroll
            for (int q = 0; q < 8; ++q) s2 += part[q][b][c];
            z[g] = s2;
        }
        const float ii = sigf(z[0]), ff = sigf(z[1]);
        const float gg = tanhf(z[2]), oo = sigf(z[3]);
        const int ci = b * U_ + u0 + uu;
        const float cv = ff * c_st[ci] + ii * gg;
        c_st[ci] = cv;
        const float hv = oo * tanhf(cv);
        const int u = u0 + uu;
        const size_t fo = ((size_t)((u >> 5) * 2 + (b >> 4)) * 64
                           + ((u >> 3) & 3) * 16 + (b & 15)) * 8 + (u & 7);
        af_w[fo] = (__bf16)hv;
    }
}

// ---------------------------------------------------------------------------
// Cell-1 z (fp32, off critical path): Pc[b][col] = x_last @ k1 + b1.
// ---------------------------------------------------------------------------
__global__ __launch_bounds__(256) void cell1_gemm(
    const int* __restrict__ tokens, const float* __restrict__ emb,
    const float* __restrict__ k1, const float* __restrict__ b1,
    float* __restrict__ Pc)
{
    const int tid  = threadIdx.x;
    const int lane = tid & 63;
    const int warp = tid >> 6;
    const int j  = blockIdx.x;
    const int ct = j & 15, bg = j >> 4;
    const int b  = bg * 4 + warp;
    const int col = ct * 256 + lane * 4;
    const int tok = tokens[b * T_ + (T_ - 1)];
    const float* wp = k1 + col;
    const float* xp = emb + (size_t)tok * E_;
    float4 acc = *reinterpret_cast<const float4*>(b1 + col);
    #pragma unroll 4
    for (int k4 = 0; k4 < 64; ++k4) {
        const float4 x4 = *reinterpret_cast<const float4*>(xp + k4 * 4);
        const float4 w0 = *reinterpret_cast<const float4*>(wp + (size_t)(k4 * 4 + 0) * FU_);
        const float4 w1 = *reinterpret_cast<const float4*>(wp + (size_t)(k4 * 4 + 1) * FU_);
        const float4 w2 = *reinterpret_cast<const float4*>(wp + (size_t)(k4 * 4 + 2) * FU_);
        const float4 w3 = *reinterpret_cast<const float4*>(wp + (size_t)(k4 * 4 + 3) * FU_);
        acc.x = fmaf(x4.x, w0.x, acc.x); acc.y = fmaf(x4.x, w0.y, acc.y);
        acc.z = fmaf(x4.x, w0.z, acc.z); acc.w = fmaf(x4.x, w0.w, acc.w);
        acc.x = fmaf(x4.y, w1.x, acc.x); acc.y = fmaf(x4.y, w1.y, acc.y);
        acc.z = fmaf(x4.y, w1.z, acc.z); acc.w = fmaf(x4.y, w1.w, acc.w);
        acc.x = fmaf(x4.z, w2.x, acc.x); acc.y = fmaf(x4.z, w2.y, acc.y);
        acc.z = fmaf(x4.z, w2.z, acc.z); acc.w = fmaf(x4.z, w2.w, acc.w);
        acc.x = fmaf(x4.w, w3.x, acc.x); acc.y = fmaf(x4.w, w3.y, acc.y);
        acc.z = fmaf(x4.w, w3.z, acc.z); acc.w = fmaf(x4.w, w3.w, acc.w);
    }
    *reinterpret_cast<float4*>(Pc + (size_t)b * FU_ + col) = acc;
}

// ---------------------------------------------------------------------------
// Final: out[b] = sigmoid( h0.wout[0:U] + h1.wout[U:2U] + bout ).
// h0 from A-fragment layout (bf16 hi); h1 on the fly from Pc.
// ---------------------------------------------------------------------------
__global__ __launch_bounds__(256) void final_kernel(
    const __bf16* __restrict__ hfh,
    const float* __restrict__ Pc,
    const float* __restrict__ wout, const float* __restrict__ bout,
    float* __restrict__ out)
{
    const int b = blockIdx.x;
    const int tid = threadIdx.x;
    float s = 0.f;
    for (int u = tid; u < U_; u += 256) {
        const size_t fo = ((size_t)((u >> 5) * 2 + (b >> 4)) * 64
                           + ((u >> 3) & 3) * 16 + (b & 15)) * 8 + (u & 7);
        const float h0v = (float)hfh[fo];
        const float zi = Pc[(size_t)b * FU_ + u];
        const float zg = Pc[(size_t)b * FU_ + 2 * U_ + u];
        const float zo = Pc[(size_t)b * FU_ + 3 * U_ + u];
        const float c1 = sigf(zi) * tanhf(zg);
        const float h1 = sigf(zo) * tanhf(c1);
        s += h0v * wout[u] + h1 * wout[U_ + u];
    }
    #pragma unroll
    for (int off = 32; off > 0; off >>= 1) s += __shfl_down(s, off, 64);
    __shared__ float partf[4];
    if ((tid & 63) == 0) partf[tid >> 6] = s;
    __syncthreads();
    if (tid == 0) {
        const float tot = partf[0] + partf[1] + partf[2] + partf[3] + bout[0];
        out[b] = 1.f / (1.f + __expf(-tot));
    }
}

extern "C" void kernel_launch(void* const* d_in, const int* in_sizes, int n_in,
                              void* d_out, int out_size, void* d_ws, size_t ws_size,
                              hipStream_t stream) {
    const int*   tokens = (const int*)  d_in[0];
    const float* emb    = (const float*)d_in[1];
    const float* k0     = (const float*)d_in[2];
    const float* rk0    = (const float*)d_in[3];
    const float* b0     = (const float*)d_in[4];
    const float* k1     = (const float*)d_in[5];
    // d_in[6] = rk1 unused: cell 1 runs from zero state.
    const float* b1     = (const float*)d_in[7];
    const float* wout   = (const float*)d_in[8];
    const float* bout   = (const float*)d_in[9];
    float* out = (float*)d_out;

    const size_t BU   = (size_t)B_ * U_;             // 32768
    const size_t BFU  = (size_t)B_ * FU_;            // 131072
    const size_t AFSZ = (size_t)32 * 2 * 64 * 8;     // h-frag elems (64 KB)
    const size_t XFSZ = (size_t)T_ * 8 * 2 * 64 * 8; // x-frag elems (1.6 MB)
    const size_t WSZ  = (size_t)FU_ * VK_;           // 5242880

    float*  c    = (float*)d_ws;               // [32][1024] f32   (128 KB)
    __bf16* af0  = (__bf16*)(c + BU);          // h-frag parity0   (64 KB)
    __bf16* af1  = af0 + AFSZ;                 // h-frag parity1
    __bf16* xf   = af1 + AFSZ;                 // x-frags, all t   (1.6 MB)
    __bf16* wfh  = xf + XFSZ;                  // W frag hi (10.5 MB)
    float*  Pc   = (float*)(wfh + WSZ);        // [32][4096] f32  (512 KB)
    // ws use ~= 12.9 MB

    // zero c + h-frag parity0 (contiguous) every call (replay-safe)
    hipMemsetAsync(c, 0, BU * sizeof(float) + AFSZ * sizeof(__bf16), stream);

    wsplit_kernel<<<2560, 256, 0, stream>>>(rk0, k0, wfh);
    xsplit_all<<<T_, 256, 0, stream>>>(tokens, emb, xf);
    cell1_gemm<<<128, 256, 0, stream>>>(tokens, emb, k1, b1, Pc);

    for (int t = 0; t < T_; ++t) {
        const __bf16* ar = (t & 1) ? af1 : af0;
        __bf16*       aw = (t & 1) ? af0 : af1;
        step_fused<<<256, 512, 0, stream>>>(wfh, b0, ar, aw, xf, c, t);
    }
    // T_=250 even: t=249 reads af1, writes af0 -> final h in af0.

    final_kernel<<<B_, 256, 0, stream>>>(af0, Pc, wout, bout, out);
}